// Round 1
// baseline (148.297 us; speedup 1.0000x reference)
//
#include <hip/hip_runtime.h>
#include <hip/hip_bf16.h>

// out[b,d,r] = sum_c p[b,c] * softmax_d( x[b,:] @ W[:, c*8+d, r] + bias[c,d,r] )
// B=16384, F=128, C=8, R=64.  GEMM (17.2 GFLOP) via bf16 MFMA 16x16x32,
// softmax+contraction fused in-register (softmax-over-d lands in one lane).

#define B_ROWS   16384
#define F_DIM    128
#define NCOL     4096      // C*C*R
#define OUT_STRIDE 512     // C*R
#define LOG2E    1.44269504088896340736f

typedef __bf16 bf16x8 __attribute__((ext_vector_type(8)));
typedef float  f32x4  __attribute__((ext_vector_type(4)));

// ---------------------------------------------------------------------------
// Prepass: W fp32 (128 x 4096 row-major) -> bf16 MFMA B-fragments in ws.
// Fragment (t, kk, lane, j) holds W[k][n], k = kk*32 + (lane>>4)*8 + j,
// n = t*16 + (lane&15).  Element offset = ((t*4+kk)*64 + lane)*8 + j.
// ---------------------------------------------------------------------------
__global__ void wconv_kernel(const float* __restrict__ W, __bf16* __restrict__ wf) {
    int tid = blockIdx.x * 256 + threadIdx.x;   // 0 .. 524287, coalesced read
    int k = tid >> 12;                          // 0..127
    int n = tid & 4095;                         // 0..4095
    float v = W[tid];
    int t    = n >> 4;
    int kk   = k >> 5;
    int lane = ((k >> 3) & 3) * 16 + (n & 15);
    int j    = k & 7;
    wf[((((t << 2) + kk) << 6) + lane) * 8 + j] = (__bf16)v;
}

// ---------------------------------------------------------------------------
// Fused GEMM + bias + softmax(d) + p-contraction.
// Block: 256 thr (4 waves), 32 batch rows. Wave w owns r in [16w, 16w+16),
// all 8 d, both 16-row m-tiles.  C/D layout col=lane&15 (-> r),
// row=quad*4+reg (-> batch row): the 8 d values for one (b,r) sit in the
// same lane across the 8 d-accumulators -> softmax is per-lane scalar code.
// ---------------------------------------------------------------------------
__global__ __launch_bounds__(256, 2)
void fused_kernel(const float* __restrict__ x, const float* __restrict__ p,
                  const float* __restrict__ bias, const __bf16* __restrict__ wf,
                  float* __restrict__ out) {
    const int lane = threadIdx.x & 63;
    const int w    = threadIdx.x >> 6;   // r-chunk 0..3
    const int quad = lane >> 4;
    const int l15  = lane & 15;
    const int b0   = blockIdx.x * 32;

    // ---- A fragments (x rows, bf16), hoisted: reused across all 8 c-bands.
    // afr[m][kk][j] = x_bf16[b0 + m*16 + l15][kk*32 + quad*8 + j]
    bf16x8 afr[2][4];
    for (int m = 0; m < 2; ++m) {
        const float* xr = x + (b0 + m * 16 + l15) * F_DIM + quad * 8;
        for (int kk = 0; kk < 4; ++kk) {
            float4 lo = *(const float4*)(xr + kk * 32);
            float4 hi = *(const float4*)(xr + kk * 32 + 4);
            bf16x8 f;
            f[0] = (__bf16)lo.x; f[1] = (__bf16)lo.y;
            f[2] = (__bf16)lo.z; f[3] = (__bf16)lo.w;
            f[4] = (__bf16)hi.x; f[5] = (__bf16)hi.y;
            f[6] = (__bf16)hi.z; f[7] = (__bf16)hi.w;
            afr[m][kk] = f;
        }
    }

    float O[2][8][4] = {};   // [m][d][reg] output accumulator over c

#pragma unroll 1
    for (int c = 0; c < 8; ++c) {
        // bias for this wave's r-range (per-lane, 8 d values)
        float bv[8];
        for (int d = 0; d < 8; ++d)
            bv[d] = bias[(c * 8 + d) * 64 + w * 16 + l15];
        // p for the 8 batch rows this lane touches
        float pv[2][4];
        for (int m = 0; m < 2; ++m)
            for (int jj = 0; jj < 4; ++jj)
                pv[m][jj] = p[(b0 + m * 16 + quad * 4 + jj) * 8 + c];

        f32x4 acc[2][8] = {};
        for (int kk = 0; kk < 4; ++kk) {
            for (int d = 0; d < 8; ++d) {
                const int t = (c * 8 + d) * 4 + w;   // 16-col tile index
                bf16x8 bfr = *(const bf16x8*)(wf + ((((t << 2) + kk) << 6) + lane) * 8);
                acc[0][d] = __builtin_amdgcn_mfma_f32_16x16x32_bf16(
                                afr[0][kk], bfr, acc[0][d], 0, 0, 0);
                acc[1][d] = __builtin_amdgcn_mfma_f32_16x16x32_bf16(
                                afr[1][kk], bfr, acc[1][d], 0, 0, 0);
            }
        }

        // epilogue: softmax over d (all in this lane), weight by p, accumulate
        for (int m = 0; m < 2; ++m) {
            for (int jj = 0; jj < 4; ++jj) {
                float e[8];
                float s = 0.f;
                for (int d = 0; d < 8; ++d) {
                    e[d] = exp2f((acc[m][d][jj] + bv[d]) * LOG2E);
                    s += e[d];
                }
                float scale = pv[m][jj] / s;
                for (int d = 0; d < 8; ++d)
                    O[m][d][jj] += e[d] * scale;
            }
        }
    }

    // ---- write out: out[b, d*64 + r], row stride 512
    for (int m = 0; m < 2; ++m) {
        for (int jj = 0; jj < 4; ++jj) {
            float* orow = out + (b0 + m * 16 + quad * 4 + jj) * OUT_STRIDE
                              + w * 16 + l15;
            for (int d = 0; d < 8; ++d)
                orow[d * 64] = O[m][d][jj];
        }
    }
}

extern "C" void kernel_launch(void* const* d_in, const int* in_sizes, int n_in,
                              void* d_out, int out_size, void* d_ws, size_t ws_size,
                              hipStream_t stream) {
    const float* x    = (const float*)d_in[0];   // (16384, 128)
    const float* p    = (const float*)d_in[1];   // (16384, 8)
    const float* W    = (const float*)d_in[2];   // (128, 64, 64)
    const float* bias = (const float*)d_in[3];   // (8, 8, 64)
    float* out = (float*)d_out;                  // (16384, 8, 64)
    __bf16* wf = (__bf16*)d_ws;                  // 1 MB bf16 fragments

    wconv_kernel<<<dim3(NCOL * F_DIM / 256), dim3(256), 0, stream>>>(W, wf);
    fused_kernel<<<dim3(B_ROWS / 32), dim3(256), 0, stream>>>(x, p, bias, wf, out);
}